// Round 11
// baseline (261.112 us; speedup 1.0000x reference)
//
#include <hip/hip_runtime.h>
#include <hip/hip_bf16.h>

#define NN 100000
#define EE 1600000
#define MM 1700000          // EE + NN self loops
#define CH 8192             // edges per sort block
#define NBLK 208            // ceil(MM/CH)
#define N1 106496           // 512 * NBLK (scan domain)
#define NBKT 391            // ceil(NN/256)
#define NCONV 38024         // 21640 f32 conv + 8192 wt1 + 8192 wt2
#define NBG1 1563           // ceil(NN/64) gemm1 blocks

typedef unsigned short u16;
typedef __attribute__((ext_vector_type(8))) short bf16x8;
typedef __attribute__((ext_vector_type(4))) float f32x4;
typedef __attribute__((ext_vector_type(2))) float f32x2v;

__device__ __forceinline__ float bf2f(u16 u){ return __uint_as_float(((unsigned)u) << 16); }
__device__ __forceinline__ float bf2f_lo(unsigned u){ return __uint_as_float(u << 16); }
__device__ __forceinline__ float bf2f_hi(unsigned u){ return __uint_as_float(u & 0xFFFF0000u); }

__device__ __forceinline__ unsigned f2bf(float f){   // round-to-nearest-even
  unsigned x = __float_as_uint(f);
  unsigned r = x + 0x7FFFu + ((x >> 16) & 1u);
  return (r >> 16);
}

// per-wave dtype detection (reads first 64 samples; L2-hot, ~free)
__device__ __forceinline__ int detect_bf(const u16* __restrict__ x16){
  int lane = threadIdx.x & 63;
  u16 u = x16[2 * lane];
  int eb = (u >> 8) & 0x7F;
  unsigned long long b = __ballot(eb >= 0x3A && eb <= 0x41);
  return __popcll(b) >= 32;
}
__device__ __forceinline__ int detect_i64(const int* __restrict__ ei32){
  int lane = threadIdx.x & 63;
  unsigned long long b = __ballot(ei32[2 * lane + 1] == 0);
  return __popcll(b) >= 32;
}

__device__ __forceinline__ float wred(float v){
  v += __shfl_xor(v, 32, 64);
  v += __shfl_xor(v, 16, 64);
  v += __shfl_xor(v, 8, 64);
  v += __shfl_xor(v, 4, 64);
  v += __shfl_xor(v, 2, 64);
  v += __shfl_xor(v, 1, 64);
  return v;
}

__device__ __forceinline__ float hwred(float v){   // 32-lane (within half-wave) reduce
  v += __shfl_xor(v, 16, 64);
  v += __shfl_xor(v, 8, 64);
  v += __shfl_xor(v, 4, 64);
  v += __shfl_xor(v, 2, 64);
  v += __shfl_xor(v, 1, 64);
  return v;
}

__device__ __forceinline__ float eluf(float v){ return (v > 0.f) ? v : (__expf(v) - 1.f); }

__device__ __forceinline__ void acc_bf8p(f32x2v* acc, uint4 q, float w){
  f32x2v wv = {w, w};
  f32x2v h0 = {bf2f_lo(q.x), bf2f_hi(q.x)};
  f32x2v h1 = {bf2f_lo(q.y), bf2f_hi(q.y)};
  f32x2v h2 = {bf2f_lo(q.z), bf2f_hi(q.z)};
  f32x2v h3 = {bf2f_lo(q.w), bf2f_hi(q.w)};
  acc[0] += wv * h0;   // contracts to v_pk_fma_f32
  acc[1] += wv * h1;
  acc[2] += wv * h2;
  acc[3] += wv * h3;
}

// ---------------- ws guard sentinel ----------------
__global__ void k_fill(float* __restrict__ o, int n){
  int i = blockIdx.x * blockDim.x + threadIdx.x;
  if (i < n) o[i] = 12345.0f;
}

// ---------------- sort pass A: coarse histogram (vectorized) + weight conversion ----------------
__global__ __launch_bounds__(256) void k_hist1(const int* __restrict__ ei, const u16* __restrict__ x16,
                        int* __restrict__ ghist,
                        const void* s0, const void* s1, const void* s2, const void* s3,
                        const void* s4, const void* s5, const void* s6, const void* s7,
                        const void* s8, const void* s9, const void* s10, const void* s11,
                        float* __restrict__ dst, u16* __restrict__ wt1, u16* __restrict__ wt2){
  __shared__ int hsh[512];
  int b = blockIdx.x;
  if (b < NBLK){
    for (int i = threadIdx.x; i < 512; i += 256) hsh[i] = 0;
    int i64 = detect_i64(ei);
    __syncthreads();
    #pragma unroll
    for (int k = 0; k < 8; ++k){
      int i0 = b * CH + k * 1024 + threadIdx.x * 4;
      if (i0 >= MM) break;
      if (i0 + 3 < EE){
        if (i64){
          int4 q0 = *(const int4*)&ei[2 * (EE + i0)];
          int4 q1 = *(const int4*)&ei[2 * (EE + i0) + 4];
          atomicAdd(&hsh[q0.x >> 8], 1); atomicAdd(&hsh[q0.z >> 8], 1);
          atomicAdd(&hsh[q1.x >> 8], 1); atomicAdd(&hsh[q1.z >> 8], 1);
        } else {
          int4 q = *(const int4*)&ei[EE + i0];
          atomicAdd(&hsh[q.x >> 8], 1); atomicAdd(&hsh[q.y >> 8], 1);
          atomicAdd(&hsh[q.z >> 8], 1); atomicAdd(&hsh[q.w >> 8], 1);
        }
      } else {
        for (int t = 0; t < 4; ++t){
          int i = i0 + t;
          if (i >= MM) break;
          int d;
          if (i < EE) d = i64 ? ei[2 * (EE + i)] : ei[EE + i];
          else        d = i - EE;
          atomicAdd(&hsh[d >> 8], 1);
        }
      }
    }
    __syncthreads();
    for (int i = threadIdx.x; i < 512; i += 256) ghist[i * NBLK + b] = hsh[i];
    return;
  }
  int i = (b - NBLK) * 256 + threadIdx.x;
  if (i >= NCONV) return;
  int bf = detect_bf(x16);
  if (i < 21640){
    const int offs[13] = {0,8192,8320,8448,8576,16768,16832,16896,16960,21056,21120,21632,21640};
    const void* srcs[12] = {s0,s1,s2,s3,s4,s5,s6,s7,s8,s9,s10,s11};
    int seg = 0;
    while (i >= offs[seg + 1]) seg++;
    int j = i - offs[seg];
    float v = bf ? bf2f(((const u16*)srcs[seg])[j]) : ((const float*)srcs[seg])[j];
    dst[i] = v;
  } else if (i < 29832){
    int i2 = i - 21640;                 // wt1[c][k] = W1[k][c], c<128, k<64
    int c = i2 >> 6, k = i2 & 63;
    int si = k * 128 + c;
    wt1[i2] = bf ? ((const u16*)s0)[si] : (u16)f2bf(((const float*)s0)[si]);
  } else {
    int i3 = i - 29832;                 // wt2[c][k] = W2[k][c], c<64, k<128
    int c = i3 >> 7, k = i3 & 127;
    int si = k * 64 + c;
    wt2[i3] = bf ? ((const u16*)s4)[si] : (u16)f2bf(((const float*)s4)[si]);
  }
}

// ---------------- generic scan over ghist[N1] -> incl, bsums ----------------
__global__ __launch_bounds__(1024) void k_gscan1(const int* __restrict__ ghist, int* __restrict__ incl,
                                                 int* __restrict__ bsums){
  __shared__ int s[1024];
  int i = blockIdx.x * 1024 + threadIdx.x;
  int v = (i < N1) ? ghist[i] : 0;
  s[threadIdx.x] = v;
  __syncthreads();
  for (int off = 1; off < 1024; off <<= 1){
    int t = (threadIdx.x >= off) ? s[threadIdx.x - off] : 0;
    __syncthreads();
    s[threadIdx.x] += t;
    __syncthreads();
  }
  if (i < N1) incl[i] = s[threadIdx.x];
  if (threadIdx.x == 1023) bsums[blockIdx.x] = s[1023];
}

__global__ void k_scan2(int* __restrict__ bsums, int nb){   // nb <= 128
  __shared__ int s[128];
  int t = threadIdx.x;
  int v = (t < nb) ? bsums[t] : 0;
  s[t] = v;
  __syncthreads();
  for (int off = 1; off < 128; off <<= 1){
    int x = (t >= off) ? s[t - off] : 0;
    __syncthreads();
    s[t] += x;
    __syncthreads();
  }
  if (t < nb) bsums[t] = s[t];
}

__global__ __launch_bounds__(256) void k_gscan3(const int* __restrict__ incl, const int* __restrict__ ghist,
                                                const int* __restrict__ bsums, int* __restrict__ off1){
  int i = blockIdx.x * blockDim.x + threadIdx.x;
  if (i >= N1) return;
  int b = i >> 10;
  int base = b ? bsums[b - 1] : 0;
  off1[i] = base + incl[i] - ghist[i];    // exclusive
}

// ---------------- fused: sort scatter (blocks [0,NBLK)) + GEMM1 MFMA (blocks [NBLK,...)) ----------------
__global__ __launch_bounds__(256) void k_scat_gemm1(
    const int* __restrict__ ei, const int* __restrict__ off1, unsigned* __restrict__ e1,
    const void* __restrict__ xv, const u16* __restrict__ wt1,
    const float* __restrict__ asw, const float* __restrict__ adw,
    u16* __restrict__ h1bf, float* __restrict__ AS, float* __restrict__ AD, int n){
  __shared__ int offs[512];
  __shared__ int cnt[512];
  int b = blockIdx.x;
  if (b < NBLK){
    int i64 = detect_i64(ei);
    for (int i = threadIdx.x; i < 512; i += 256){
      offs[i] = off1[i * NBLK + b];
      cnt[i] = 0;
    }
    __syncthreads();
    #pragma unroll
    for (int k = 0; k < 8; ++k){
      int i0 = b * CH + k * 1024 + threadIdx.x * 4;
      if (i0 >= MM) break;
      int sv[4], dv[4];
      int cntv = 4;
      if (i0 + 3 < EE){
        if (i64){
          int4 a0 = *(const int4*)&ei[2 * i0];
          int4 a1 = *(const int4*)&ei[2 * i0 + 4];
          int4 b0 = *(const int4*)&ei[2 * (EE + i0)];
          int4 b1 = *(const int4*)&ei[2 * (EE + i0) + 4];
          sv[0]=a0.x; sv[1]=a0.z; sv[2]=a1.x; sv[3]=a1.z;
          dv[0]=b0.x; dv[1]=b0.z; dv[2]=b1.x; dv[3]=b1.z;
        } else {
          int4 a = *(const int4*)&ei[i0];
          int4 d = *(const int4*)&ei[EE + i0];
          sv[0]=a.x; sv[1]=a.y; sv[2]=a.z; sv[3]=a.w;
          dv[0]=d.x; dv[1]=d.y; dv[2]=d.z; dv[3]=d.w;
        }
      } else {
        cntv = 0;
        for (int t = 0; t < 4; ++t){
          int i = i0 + t;
          if (i >= MM) break;
          if (i < EE){
            if (i64){ sv[cntv] = ei[2 * i]; dv[cntv] = ei[2 * (EE + i)]; }
            else    { sv[cntv] = ei[i];     dv[cntv] = ei[EE + i]; }
          } else { sv[cntv] = i - EE; dv[cntv] = i - EE; }
          cntv++;
        }
      }
      for (int t = 0; t < cntv; ++t){
        int bin = dv[t] >> 8;
        int r = atomicAdd(&cnt[bin], 1);
        e1[offs[bin] + r] = ((unsigned)sv[t] << 8) | ((unsigned)dv[t] & 255u);
      }
    }
    return;
  }
  // ---- GEMM1 (MFMA, zero LDS) + fused att1 ----
  int bf = detect_bf((const u16*)xv);
  int tid = threadIdx.x;
  int wv = tid >> 6, l = tid & 63;
  int lm = l & 15, lk = l >> 4;          // lk 0..3
  int M0 = (b - NBLK) * 64 + wv * 16;
  int row = M0 + lm; if (row >= n) row = n - 1;
  bf16x8 a0, a1;
  if (bf){
    const u16* xp = (const u16*)xv + (size_t)row * 64;
    union { uint4 u; bf16x8 v; } c0, c1;
    c0.u = *(const uint4*)&xp[lk * 8];
    c1.u = *(const uint4*)&xp[32 + lk * 8];
    a0 = c0.v; a1 = c1.v;
  } else {
    const float* xp = (const float*)xv + (size_t)row * 64;
    float4 f0 = *(const float4*)&xp[lk * 8];
    float4 f1 = *(const float4*)&xp[lk * 8 + 4];
    float4 f2 = *(const float4*)&xp[32 + lk * 8];
    float4 f3 = *(const float4*)&xp[32 + lk * 8 + 4];
    union { u16 s[8]; bf16x8 v; } p0, p1;
    p0.s[0]=(u16)f2bf(f0.x); p0.s[1]=(u16)f2bf(f0.y); p0.s[2]=(u16)f2bf(f0.z); p0.s[3]=(u16)f2bf(f0.w);
    p0.s[4]=(u16)f2bf(f1.x); p0.s[5]=(u16)f2bf(f1.y); p0.s[6]=(u16)f2bf(f1.z); p0.s[7]=(u16)f2bf(f1.w);
    p1.s[0]=(u16)f2bf(f2.x); p1.s[1]=(u16)f2bf(f2.y); p1.s[2]=(u16)f2bf(f2.z); p1.s[3]=(u16)f2bf(f2.w);
    p1.s[4]=(u16)f2bf(f3.x); p1.s[5]=(u16)f2bf(f3.y); p1.s[6]=(u16)f2bf(f3.z); p1.s[7]=(u16)f2bf(f3.w);
    a0 = p0.v; a1 = p1.v;
  }
  f32x4 acc[8];
  #pragma unroll
  for (int nt = 0; nt < 8; ++nt) acc[nt] = (f32x4){0.f, 0.f, 0.f, 0.f};
  #pragma unroll
  for (int nt = 0; nt < 8; ++nt){
    int col = nt * 16 + lm;
    union { uint4 u; bf16x8 v; } b0, b1;
    b0.u = *(const uint4*)&wt1[(size_t)col * 64 + lk * 8];
    b1.u = *(const uint4*)&wt1[(size_t)col * 64 + 32 + lk * 8];
    acc[nt] = __builtin_amdgcn_mfma_f32_16x16x32_bf16(a0, b0.v, acc[nt], 0, 0, 0);
    acc[nt] = __builtin_amdgcn_mfma_f32_16x16x32_bf16(a1, b1.v, acc[nt], 0, 0, 0);
  }
  float ps0[4] = {0,0,0,0}, pd0[4] = {0,0,0,0}, ps1[4] = {0,0,0,0}, pd1[4] = {0,0,0,0};
  #pragma unroll
  for (int nt = 0; nt < 8; ++nt){
    int col = nt * 16 + lm;
    float aw = asw[col], dw = adw[col];
    #pragma unroll
    for (int i = 0; i < 4; ++i){
      float v = acc[nt][i];
      if (nt < 4){ ps0[i] += v * aw; pd0[i] += v * dw; }
      else       { ps1[i] += v * aw; pd1[i] += v * dw; }
    }
  }
  #pragma unroll
  for (int mk = 8; mk >= 1; mk >>= 1){
    #pragma unroll
    for (int i = 0; i < 4; ++i){
      ps0[i] += __shfl_xor(ps0[i], mk, 64); pd0[i] += __shfl_xor(pd0[i], mk, 64);
      ps1[i] += __shfl_xor(ps1[i], mk, 64); pd1[i] += __shfl_xor(pd1[i], mk, 64);
    }
  }
  #pragma unroll
  for (int nt = 0; nt < 8; ++nt){
    int col = nt * 16 + lm;
    #pragma unroll
    for (int i = 0; i < 4; ++i){
      int r = M0 + lk * 4 + i;
      if (r < n) h1bf[(size_t)r * 128 + col] = (u16)f2bf(acc[nt][i]);
    }
  }
  if (lm == 0){
    #pragma unroll
    for (int i = 0; i < 4; ++i){
      int r = M0 + lk * 4 + i;
      if (r < n){
        AS[r * 2] = ps0[i]; AS[r * 2 + 1] = ps1[i];
        AD[r * 2] = pd0[i]; AD[r * 2 + 1] = pd1[i];
      }
    }
  }
}

// ---------------- sort pass B: one block per 256-node bucket ----------------
__global__ __launch_bounds__(256) void k_pass2(const unsigned* __restrict__ e1, const int* __restrict__ off1,
                                               int* __restrict__ csr, int* __restrict__ rp){
  __shared__ int hh[256];
  __shared__ int cc[256];
  int bu = blockIdx.x;
  int t = threadIdx.x;
  int s = off1[bu * NBLK];
  int e = off1[(bu + 1) * NBLK];
  hh[t] = 0; cc[t] = 0;
  __syncthreads();
  for (int j = s + t; j < e; j += 256)
    atomicAdd(&hh[e1[j] & 255u], 1);
  __syncthreads();
  int own = hh[t];
  for (int off = 1; off < 256; off <<= 1){
    int x = (t >= off) ? hh[t - off] : 0;
    __syncthreads();
    hh[t] += x;
    __syncthreads();
  }
  int excl = hh[t] - own;
  hh[t] = excl;
  int node = (bu << 8) + t;
  if (node < NN) rp[node] = s + excl;
  if (bu == 0 && t == 0) rp[NN] = MM;
  __syncthreads();
  for (int j = s + t; j < e; j += 256){
    unsigned kv = e1[j];
    int d = kv & 255u;
    int r = atomicAdd(&cc[d], 1);
    csr[s + hh[d] + r] = (int)(kv >> 8);
  }
}

// ---------------- layer-1 aggregation: 2 nodes/wave, 8 gathers in flight -> h1bbf (bf16) ----------------
__global__ __launch_bounds__(256) void k_agg1(const u16* __restrict__ h1bf, const int* __restrict__ rp,
                                              const int* __restrict__ csr, const float* __restrict__ AS,
                                              const float* __restrict__ AD, const float* __restrict__ b1,
                                              u16* __restrict__ out, int n){
  int tid = threadIdx.x;
  int wid = (blockIdx.x * 256 + tid) >> 6;
  int h = (tid >> 5) & 1;
  int l5 = tid & 31;
  int node = wid * 2 + h;
  bool valid = node < n;
  if (!valid) node = n - 1;
  int g = l5 >> 4, u = l5 & 15;
  int hb = h * 32;
  int beg = rp[node], end = rp[node + 1];
  float2 adv = *(const float2*)&AD[node * 2];
  f32x2v acc[4] = {{0,0},{0,0},{0,0},{0,0}};
  float zp0 = 0.f, zp1 = 0.f;
  for (int c = beg; c < end; c += 32){
    int m = end - c; if (m > 32) m = 32;
    int s_l = 0; float w0_l = 0.f, w1_l = 0.f;
    if (l5 < m){
      s_l = csr[c + l5];
      float2 as2 = *(const float2*)&AS[s_l * 2];
      float e0 = as2.x + adv.x; e0 = fmaxf(e0, 0.2f * e0);
      float e1 = as2.y + adv.y; e1 = fmaxf(e1, 0.2f * e1);
      w0_l = __expf(e0); w1_l = __expf(e1);
    }
    zp0 += w0_l; zp1 += w1_l;
    for (int jj = 0; jj < m; jj += 16){
      bool vv[8]; int ss[8]; float ww[8];
      #pragma unroll
      for (int t = 0; t < 8; ++t){
        int e = jj + t * 2 + g;
        vv[t] = e < m;
        ss[t] = __shfl(s_l, hb + e, 64);
        float w0 = __shfl(w0_l, hb + e, 64);
        float w1 = __shfl(w1_l, hb + e, 64);
        ww[t] = (u < 8) ? w0 : w1;
      }
      uint4 qq[8];
      #pragma unroll
      for (int t = 0; t < 8; ++t)
        if (vv[t]) qq[t] = *(const uint4*)&h1bf[(size_t)ss[t] * 128 + u * 8];
      #pragma unroll
      for (int t = 0; t < 8; ++t)
        if (vv[t]) acc_bf8p(acc, qq[t], ww[t]);
    }
  }
  #pragma unroll
  for (int k = 0; k < 4; ++k){
    acc[k][0] += __shfl_xor(acc[k][0], 16, 64);
    acc[k][1] += __shfl_xor(acc[k][1], 16, 64);
  }
  float z0 = hwred(zp0), z1 = hwred(zp1);
  float rz = (u < 8) ? (1.f / (z0 + 1e-16f)) : (1.f / (z1 + 1e-16f));
  if (g == 0 && valid){
    float4 ba = *(const float4*)&b1[u * 8];
    float4 bb = *(const float4*)&b1[u * 8 + 4];
    float o0 = eluf(acc[0][0] * rz + ba.x), o1 = eluf(acc[0][1] * rz + ba.y);
    float o2 = eluf(acc[1][0] * rz + ba.z), o3 = eluf(acc[1][1] * rz + ba.w);
    float o4 = eluf(acc[2][0] * rz + bb.x), o5 = eluf(acc[2][1] * rz + bb.y);
    float o6 = eluf(acc[3][0] * rz + bb.z), o7 = eluf(acc[3][1] * rz + bb.w);
    uint4 pk;
    pk.x = f2bf(o0) | (f2bf(o1) << 16);
    pk.y = f2bf(o2) | (f2bf(o3) << 16);
    pk.z = f2bf(o4) | (f2bf(o5) << 16);
    pk.w = f2bf(o6) | (f2bf(o7) << 16);
    *(uint4*)&out[(size_t)node * 128 + u * 8] = pk;
  }
}

// ---------------- GEMM2 (MFMA) + fused att2: h2bf[N,64] = h1bbf@W2 ----------------
__global__ __launch_bounds__(256) void k_gemm2(const u16* __restrict__ hin, const u16* __restrict__ wt2,
                                               const float* __restrict__ asw, const float* __restrict__ adw,
                                               u16* __restrict__ h2bf, float* __restrict__ AS, float* __restrict__ AD,
                                               int n){
  int tid = threadIdx.x;
  int wv = tid >> 6, l = tid & 63;
  int lm = l & 15, lk = l >> 4;
  int M0 = blockIdx.x * 64 + wv * 16;
  int row = M0 + lm; if (row >= n) row = n - 1;
  const u16* hp = hin + (size_t)row * 128;
  bf16x8 a[4];
  #pragma unroll
  for (int kt = 0; kt < 4; ++kt){
    union { uint4 u; bf16x8 v; } c;
    c.u = *(const uint4*)&hp[kt * 32 + lk * 8];
    a[kt] = c.v;
  }
  f32x4 acc[4];
  #pragma unroll
  for (int nt = 0; nt < 4; ++nt) acc[nt] = (f32x4){0.f, 0.f, 0.f, 0.f};
  #pragma unroll
  for (int nt = 0; nt < 4; ++nt){
    int col = nt * 16 + lm;
    #pragma unroll
    for (int kt = 0; kt < 4; ++kt){
      union { uint4 u; bf16x8 v; } b;
      b.u = *(const uint4*)&wt2[(size_t)col * 128 + kt * 32 + lk * 8];
      acc[nt] = __builtin_amdgcn_mfma_f32_16x16x32_bf16(a[kt], b.v, acc[nt], 0, 0, 0);
    }
  }
  float ps[4] = {0,0,0,0}, pd[4] = {0,0,0,0};
  #pragma unroll
  for (int nt = 0; nt < 4; ++nt){
    int col = nt * 16 + lm;
    float aw = asw[col], dw = adw[col];
    #pragma unroll
    for (int i = 0; i < 4; ++i){
      float v = acc[nt][i];
      ps[i] += v * aw; pd[i] += v * dw;
    }
  }
  #pragma unroll
  for (int mk = 8; mk >= 1; mk >>= 1){
    #pragma unroll
    for (int i = 0; i < 4; ++i){
      ps[i] += __shfl_xor(ps[i], mk, 64); pd[i] += __shfl_xor(pd[i], mk, 64);
    }
  }
  #pragma unroll
  for (int nt = 0; nt < 4; ++nt){
    int col = nt * 16 + lm;
    #pragma unroll
    for (int i = 0; i < 4; ++i){
      int r = M0 + lk * 4 + i;
      if (r < n) h2bf[(size_t)r * 64 + col] = (u16)f2bf(acc[nt][i]);
    }
  }
  if (lm == 0){
    #pragma unroll
    for (int i = 0; i < 4; ++i){
      int r = M0 + lk * 4 + i;
      if (r < n){ AS[r] = ps[i]; AD[r] = pd[i]; }
    }
  }
}

// ---------------- layer-2 aggregation: 2 nodes/wave, 8 slots (32 edges/node/iter) -> hb bf16 ----------------
__global__ __launch_bounds__(256) void k_agg2(const u16* __restrict__ h2bf, const int* __restrict__ rp,
                                              const int* __restrict__ csr, const float* __restrict__ AS,
                                              const float* __restrict__ AD, const float* __restrict__ b2,
                                              u16* __restrict__ hb, int n){
  int tid = threadIdx.x;
  int wid = (blockIdx.x * 256 + tid) >> 6;
  int h = (tid >> 5) & 1;
  int l5 = tid & 31;
  int node = wid * 2 + h;
  bool valid = node < n;
  if (!valid) node = n - 1;
  int g = l5 >> 3, u = l5 & 7;          // 4 edge-groups x 8 feature lanes per node
  int hwb = h * 32;
  int beg = rp[node], end = rp[node + 1];
  float ad = AD[node];
  f32x2v acc[4] = {{0,0},{0,0},{0,0},{0,0}};
  float zp = 0.f;
  for (int c = beg; c < end; c += 32){
    int m = end - c; if (m > 32) m = 32;
    int s_l = 0; float w_l = 0.f;
    if (l5 < m){
      s_l = csr[c + l5];
      float e = AS[s_l] + ad; e = fmaxf(e, 0.2f * e);
      w_l = __expf(e);
    }
    zp += w_l;
    bool vv[8]; int ss[8]; float ww[8];
    #pragma unroll
    for (int t = 0; t < 8; ++t){
      int e = t * 4 + g;
      vv[t] = e < m;
      ss[t] = __shfl(s_l, hwb + e, 64);
      ww[t] = __shfl(w_l, hwb + e, 64);
    }
    uint4 qq[8];
    #pragma unroll
    for (int t = 0; t < 8; ++t)
      if (vv[t]) qq[t] = *(const uint4*)&h2bf[(size_t)ss[t] * 64 + u * 8];
    #pragma unroll
    for (int t = 0; t < 8; ++t)
      if (vv[t]) acc_bf8p(acc, qq[t], ww[t]);
  }
  #pragma unroll
  for (int k = 0; k < 4; ++k){
    acc[k][0] += __shfl_xor(acc[k][0], 8, 64);
    acc[k][1] += __shfl_xor(acc[k][1], 8, 64);
    acc[k][0] += __shfl_xor(acc[k][0], 16, 64);
    acc[k][1] += __shfl_xor(acc[k][1], 16, 64);
  }
  float z = hwred(zp);
  float rz = 1.f / (z + 1e-16f);
  if (g == 0 && valid){
    float4 ba = *(const float4*)&b2[u * 8];
    float4 bb = *(const float4*)&b2[u * 8 + 4];
    float o0 = eluf(acc[0][0] * rz + ba.x), o1 = eluf(acc[0][1] * rz + ba.y);
    float o2 = eluf(acc[1][0] * rz + ba.z), o3 = eluf(acc[1][1] * rz + ba.w);
    float o4 = eluf(acc[2][0] * rz + bb.x), o5 = eluf(acc[2][1] * rz + bb.y);
    float o6 = eluf(acc[3][0] * rz + bb.z), o7 = eluf(acc[3][1] * rz + bb.w);
    uint4 pk;
    pk.x = f2bf(o0) | (f2bf(o1) << 16);
    pk.y = f2bf(o2) | (f2bf(o3) << 16);
    pk.z = f2bf(o4) | (f2bf(o5) << 16);
    pk.w = f2bf(o6) | (f2bf(o7) << 16);
    *(uint4*)&hb[(size_t)node * 64 + u * 8] = pk;
  }
}

// ---------------- MLP head: node-per-lane, scalar-load weights, zero LDS ----------------
__global__ __launch_bounds__(256) void k_mlp(const u16* __restrict__ hb, const u16* __restrict__ x16,
                                             const float* __restrict__ m1w, const float* __restrict__ m1b,
                                             const float* __restrict__ m2w, const float* __restrict__ m2b,
                                             void* __restrict__ outv, int n){
  int bf = detect_bf(x16);
  int node = blockIdx.x * 256 + threadIdx.x;
  bool act = node < n;
  const u16* hp = hb + (size_t)(act ? node : 0) * 64;
  float acc[64];
  #pragma unroll
  for (int j = 0; j < 64; ++j) acc[j] = m1b[j];
  #pragma unroll
  for (int kc = 0; kc < 8; ++kc){
    uint4 q = *(const uint4*)&hp[kc * 8];
    float hk[8] = {bf2f_lo(q.x), bf2f_hi(q.x), bf2f_lo(q.y), bf2f_hi(q.y),
                   bf2f_lo(q.z), bf2f_hi(q.z), bf2f_lo(q.w), bf2f_hi(q.w)};
    #pragma unroll
    for (int t = 0; t < 8; ++t){
      const float* wr = &m1w[(kc * 8 + t) * 64];
      #pragma unroll
      for (int j = 0; j < 64; ++j) acc[j] += hk[t] * wr[j];
    }
  }
  float o[8];
  #pragma unroll
  for (int c = 0; c < 8; ++c) o[c] = m2b[c];
  #pragma unroll
  for (int j = 0; j < 64; ++j){
    float r = fmaxf(acc[j], 0.f);
    const float* w2r = &m2w[j * 8];
    #pragma unroll
    for (int c = 0; c < 8; ++c) o[c] += r * w2r[c];
  }
  if (act){
    if (bf){
      uint4 pk;
      pk.x = f2bf(fmaxf(o[0], 0.f)) | (f2bf(fmaxf(o[1], 0.f)) << 16);
      pk.y = f2bf(fmaxf(o[2], 0.f)) | (f2bf(fmaxf(o[3], 0.f)) << 16);
      pk.z = f2bf(fmaxf(o[4], 0.f)) | (f2bf(fmaxf(o[5], 0.f)) << 16);
      pk.w = f2bf(fmaxf(o[6], 0.f)) | (f2bf(fmaxf(o[7], 0.f)) << 16);
      *(uint4*)&((u16*)outv)[(size_t)node * 8] = pk;
    } else {
      float4 a, b;
      a.x = fmaxf(o[0], 0.f); a.y = fmaxf(o[1], 0.f); a.z = fmaxf(o[2], 0.f); a.w = fmaxf(o[3], 0.f);
      b.x = fmaxf(o[4], 0.f); b.y = fmaxf(o[5], 0.f); b.z = fmaxf(o[6], 0.f); b.w = fmaxf(o[7], 0.f);
      *(float4*)&((float*)outv)[(size_t)node * 8]     = a;
      *(float4*)&((float*)outv)[(size_t)node * 8 + 4] = b;
    }
  }
}

// ---------------- host ----------------
extern "C" void kernel_launch(void* const* d_in, const int* in_sizes, int n_in,
                              void* d_out, int out_size, void* d_ws, size_t ws_size,
                              hipStream_t stream){
  const void* x   = d_in[0];
  const void* ei  = d_in[1];

  char* base = (char*)d_ws;
  size_t off = 0;
  auto alloc = [&](size_t bytes) -> void* {
    void* p = base + off;
    off += (bytes + 255) & ~(size_t)255;
    return p;
  };
  float* wbuf  = (float*)alloc(21640 * 4);
  u16*   wt1   = (u16*)alloc(8192 * 2);
  u16*   wt2   = (u16*)alloc(8192 * 2);
  u16*   h1bf  = (u16*)alloc((size_t)NN * 128 * 2);   // h2bf aliases later
  u16*   h1bbf = (u16*)alloc((size_t)NN * 128 * 2);
  u16*   hbuf  = (u16*)alloc((size_t)NN * 64 * 2);
  float* AS1   = (float*)alloc((size_t)NN * 2 * 4);
  float* AD1   = (float*)alloc((size_t)NN * 2 * 4);
  float* AS2   = (float*)alloc((size_t)NN * 4);
  float* AD2   = (float*)alloc((size_t)NN * 4);
  unsigned* e1 = (unsigned*)alloc((size_t)MM * 4);
  int*   csr   = (int*)alloc((size_t)MM * 4);
  int*   rp    = (int*)alloc((size_t)(NN + 1) * 4);
  int*   ghist = (int*)alloc((size_t)N1 * 4);
  int*   incl  = (int*)alloc((size_t)N1 * 4);
  int*   off1  = (int*)alloc((size_t)N1 * 4);
  int*   bsums = (int*)alloc(128 * 4);

  if (off > ws_size){
    int nf = out_size / 2;
    k_fill<<<(nf + 255) / 256, 256, 0, stream>>>((float*)d_out, nf);
    return;
  }

  float* AS1W = wbuf + 8192;
  float* AD1W = wbuf + 8320;
  float* B1f  = wbuf + 8448;
  float* AS2W = wbuf + 16768;
  float* AD2W = wbuf + 16832;
  float* B2f  = wbuf + 16896;
  float* M1W  = wbuf + 16960;
  float* M1B  = wbuf + 21056;
  float* M2W  = wbuf + 21120;
  float* M2B  = wbuf + 21632;
  u16*   h2bf = h1bf;   // alias: h1bf dead once agg1 completes

  const int NBCONV = (NCONV + 255) / 256;   // 149

  k_hist1<<<NBLK + NBCONV, 256, 0, stream>>>((const int*)ei, (const u16*)x, ghist,
                                             d_in[2], d_in[3], d_in[4], d_in[5], d_in[6],
                                             d_in[7], d_in[8], d_in[9], d_in[10], d_in[11],
                                             d_in[12], d_in[13], wbuf, wt1, wt2);
  k_gscan1<<<N1 / 1024, 1024, 0, stream>>>(ghist, incl, bsums);
  k_scan2<<<1, 128, 0, stream>>>(bsums, N1 / 1024);
  k_gscan3<<<(N1 + 255) / 256, 256, 0, stream>>>(incl, ghist, bsums, off1);
  k_scat_gemm1<<<NBLK + NBG1, 256, 0, stream>>>((const int*)ei, off1, e1,
                                                x, wt1, AS1W, AD1W, h1bf, AS1, AD1, NN);
  k_pass2<<<NBKT, 256, 0, stream>>>(e1, off1, csr, rp);

  k_agg1<<<(NN / 2 + 3) / 4, 256, 0, stream>>>(h1bf, rp, csr, AS1, AD1, B1f, h1bbf, NN);

  k_gemm2<<<(NN + 63) / 64, 256, 0, stream>>>(h1bbf, wt2, AS2W, AD2W, h2bf, AS2, AD2, NN);
  k_agg2<<<(NN / 2 + 3) / 4, 256, 0, stream>>>(h2bf, rp, csr, AS2, AD2, B2f, hbuf, NN);
  k_mlp<<<(NN + 255) / 256, 256, 0, stream>>>(hbuf, (const u16*)x, M1W, M1B, M2W, M2B, d_out, NN);
}

// Round 12
// 251.081 us; speedup vs baseline: 1.0400x; 1.0400x over previous
//
#include <hip/hip_runtime.h>
#include <hip/hip_bf16.h>

#define NN 100000
#define EE 1600000
#define MM 1700000          // EE + NN self loops
#define CH 8192             // edges per sort block
#define NBLK 208            // ceil(MM/CH)
#define N1 106496           // 512 * NBLK (scan domain)
#define NBKT 391            // ceil(NN/256)
#define NCONV 38024         // 21640 f32 conv + 8192 wt1 + 8192 wt2
#define NBG1 1563           // ceil(NN/64) gemm1 blocks

typedef unsigned short u16;
typedef __attribute__((ext_vector_type(8))) short bf16x8;
typedef __attribute__((ext_vector_type(4))) float f32x4;
typedef __attribute__((ext_vector_type(2))) float f32x2v;

__device__ __forceinline__ float bf2f(u16 u){ return __uint_as_float(((unsigned)u) << 16); }
__device__ __forceinline__ float bf2f_lo(unsigned u){ return __uint_as_float(u << 16); }
__device__ __forceinline__ float bf2f_hi(unsigned u){ return __uint_as_float(u & 0xFFFF0000u); }

__device__ __forceinline__ unsigned f2bf(float f){   // round-to-nearest-even
  unsigned x = __float_as_uint(f);
  unsigned r = x + 0x7FFFu + ((x >> 16) & 1u);
  return (r >> 16);
}

// per-wave dtype detection (reads first 64 samples; L2-hot, ~free)
__device__ __forceinline__ int detect_bf(const u16* __restrict__ x16){
  int lane = threadIdx.x & 63;
  u16 u = x16[2 * lane];
  int eb = (u >> 8) & 0x7F;
  unsigned long long b = __ballot(eb >= 0x3A && eb <= 0x41);
  return __popcll(b) >= 32;
}
__device__ __forceinline__ int detect_i64(const int* __restrict__ ei32){
  int lane = threadIdx.x & 63;
  unsigned long long b = __ballot(ei32[2 * lane + 1] == 0);
  return __popcll(b) >= 32;
}

__device__ __forceinline__ float wred(float v){
  v += __shfl_xor(v, 32, 64);
  v += __shfl_xor(v, 16, 64);
  v += __shfl_xor(v, 8, 64);
  v += __shfl_xor(v, 4, 64);
  v += __shfl_xor(v, 2, 64);
  v += __shfl_xor(v, 1, 64);
  return v;
}

__device__ __forceinline__ float hwred(float v){   // 32-lane (within half-wave) reduce
  v += __shfl_xor(v, 16, 64);
  v += __shfl_xor(v, 8, 64);
  v += __shfl_xor(v, 4, 64);
  v += __shfl_xor(v, 2, 64);
  v += __shfl_xor(v, 1, 64);
  return v;
}

__device__ __forceinline__ float eluf(float v){ return (v > 0.f) ? v : (__expf(v) - 1.f); }

__device__ __forceinline__ void acc_bf8p(f32x2v* acc, uint4 q, float w){
  f32x2v wv = {w, w};
  f32x2v h0 = {bf2f_lo(q.x), bf2f_hi(q.x)};
  f32x2v h1 = {bf2f_lo(q.y), bf2f_hi(q.y)};
  f32x2v h2 = {bf2f_lo(q.z), bf2f_hi(q.z)};
  f32x2v h3 = {bf2f_lo(q.w), bf2f_hi(q.w)};
  acc[0] += wv * h0;   // contracts to v_pk_fma_f32
  acc[1] += wv * h1;
  acc[2] += wv * h2;
  acc[3] += wv * h3;
}

// inline exclusive offset from scan pieces: off1(idx) = base(idx) + incl[idx] - ghist[idx]
__device__ __forceinline__ int off1_at(const int* __restrict__ incl, const int* __restrict__ ghist,
                                       const int* __restrict__ bsums, int idx){
  int base = (idx >= 1024) ? bsums[(idx >> 10) - 1] : 0;
  return base + incl[idx] - ghist[idx];
}

// ---------------- ws guard sentinel ----------------
__global__ void k_fill(float* __restrict__ o, int n){
  int i = blockIdx.x * blockDim.x + threadIdx.x;
  if (i < n) o[i] = 12345.0f;
}

// ---------------- sort pass A: coarse histogram (vectorized) + weight conversion ----------------
__global__ __launch_bounds__(256) void k_hist1(const int* __restrict__ ei, const u16* __restrict__ x16,
                        int* __restrict__ ghist,
                        const void* s0, const void* s1, const void* s2, const void* s3,
                        const void* s4, const void* s5, const void* s6, const void* s7,
                        const void* s8, const void* s9, const void* s10, const void* s11,
                        float* __restrict__ dst, u16* __restrict__ wt1, u16* __restrict__ wt2){
  __shared__ int hsh[512];
  int b = blockIdx.x;
  if (b < NBLK){
    for (int i = threadIdx.x; i < 512; i += 256) hsh[i] = 0;
    int i64 = detect_i64(ei);
    __syncthreads();
    #pragma unroll
    for (int k = 0; k < 8; ++k){
      int i0 = b * CH + k * 1024 + threadIdx.x * 4;
      if (i0 >= MM) break;
      if (i0 + 3 < EE){
        if (i64){
          int4 q0 = *(const int4*)&ei[2 * (EE + i0)];
          int4 q1 = *(const int4*)&ei[2 * (EE + i0) + 4];
          atomicAdd(&hsh[q0.x >> 8], 1); atomicAdd(&hsh[q0.z >> 8], 1);
          atomicAdd(&hsh[q1.x >> 8], 1); atomicAdd(&hsh[q1.z >> 8], 1);
        } else {
          int4 q = *(const int4*)&ei[EE + i0];
          atomicAdd(&hsh[q.x >> 8], 1); atomicAdd(&hsh[q.y >> 8], 1);
          atomicAdd(&hsh[q.z >> 8], 1); atomicAdd(&hsh[q.w >> 8], 1);
        }
      } else {
        for (int t = 0; t < 4; ++t){
          int i = i0 + t;
          if (i >= MM) break;
          int d;
          if (i < EE) d = i64 ? ei[2 * (EE + i)] : ei[EE + i];
          else        d = i - EE;
          atomicAdd(&hsh[d >> 8], 1);
        }
      }
    }
    __syncthreads();
    for (int i = threadIdx.x; i < 512; i += 256) ghist[i * NBLK + b] = hsh[i];
    return;
  }
  int i = (b - NBLK) * 256 + threadIdx.x;
  if (i >= NCONV) return;
  int bf = detect_bf(x16);
  if (i < 21640){
    const int offs[13] = {0,8192,8320,8448,8576,16768,16832,16896,16960,21056,21120,21632,21640};
    const void* srcs[12] = {s0,s1,s2,s3,s4,s5,s6,s7,s8,s9,s10,s11};
    int seg = 0;
    while (i >= offs[seg + 1]) seg++;
    int j = i - offs[seg];
    float v = bf ? bf2f(((const u16*)srcs[seg])[j]) : ((const float*)srcs[seg])[j];
    dst[i] = v;
  } else if (i < 29832){
    int i2 = i - 21640;                 // wt1[c][k] = W1[k][c], c<128, k<64
    int c = i2 >> 6, k = i2 & 63;
    int si = k * 128 + c;
    wt1[i2] = bf ? ((const u16*)s0)[si] : (u16)f2bf(((const float*)s0)[si]);
  } else {
    int i3 = i - 29832;                 // wt2[c][k] = W2[k][c], c<64, k<128
    int c = i3 >> 7, k = i3 & 127;
    int si = k * 64 + c;
    wt2[i3] = bf ? ((const u16*)s4)[si] : (u16)f2bf(((const float*)s4)[si]);
  }
}

// ---------------- generic scan over ghist[N1] -> incl, bsums ----------------
__global__ __launch_bounds__(1024) void k_gscan1(const int* __restrict__ ghist, int* __restrict__ incl,
                                                 int* __restrict__ bsums){
  __shared__ int s[1024];
  int i = blockIdx.x * 1024 + threadIdx.x;
  int v = (i < N1) ? ghist[i] : 0;
  s[threadIdx.x] = v;
  __syncthreads();
  for (int off = 1; off < 1024; off <<= 1){
    int t = (threadIdx.x >= off) ? s[threadIdx.x - off] : 0;
    __syncthreads();
    s[threadIdx.x] += t;
    __syncthreads();
  }
  if (i < N1) incl[i] = s[threadIdx.x];
  if (threadIdx.x == 1023) bsums[blockIdx.x] = s[1023];
}

__global__ void k_scan2(int* __restrict__ bsums, int nb){   // nb <= 128
  __shared__ int s[128];
  int t = threadIdx.x;
  int v = (t < nb) ? bsums[t] : 0;
  s[t] = v;
  __syncthreads();
  for (int off = 1; off < 128; off <<= 1){
    int x = (t >= off) ? s[t - off] : 0;
    __syncthreads();
    s[t] += x;
    __syncthreads();
  }
  if (t < nb) bsums[t] = s[t];
}

// ---------------- fused: sort scatter (blocks [0,NBLK)) + GEMM1 MFMA (blocks [NBLK,...)) ----------------
__global__ __launch_bounds__(256) void k_scat_gemm1(
    const int* __restrict__ ei, const int* __restrict__ incl, const int* __restrict__ ghist,
    const int* __restrict__ bsums, unsigned* __restrict__ e1,
    const void* __restrict__ xv, const u16* __restrict__ wt1,
    const float* __restrict__ asw, const float* __restrict__ adw,
    u16* __restrict__ h1bf, float* __restrict__ AS, float* __restrict__ AD, int n){
  __shared__ int offs[512];
  __shared__ int cnt[512];
  int b = blockIdx.x;
  if (b < NBLK){
    int i64 = detect_i64(ei);
    for (int i = threadIdx.x; i < 512; i += 256){
      offs[i] = off1_at(incl, ghist, bsums, i * NBLK + b);
      cnt[i] = 0;
    }
    __syncthreads();
    #pragma unroll
    for (int k = 0; k < 8; ++k){
      int i0 = b * CH + k * 1024 + threadIdx.x * 4;
      if (i0 >= MM) break;
      int sv[4], dv[4];
      int cntv = 4;
      if (i0 + 3 < EE){
        if (i64){
          int4 a0 = *(const int4*)&ei[2 * i0];
          int4 a1 = *(const int4*)&ei[2 * i0 + 4];
          int4 b0 = *(const int4*)&ei[2 * (EE + i0)];
          int4 b1 = *(const int4*)&ei[2 * (EE + i0) + 4];
          sv[0]=a0.x; sv[1]=a0.z; sv[2]=a1.x; sv[3]=a1.z;
          dv[0]=b0.x; dv[1]=b0.z; dv[2]=b1.x; dv[3]=b1.z;
        } else {
          int4 a = *(const int4*)&ei[i0];
          int4 d = *(const int4*)&ei[EE + i0];
          sv[0]=a.x; sv[1]=a.y; sv[2]=a.z; sv[3]=a.w;
          dv[0]=d.x; dv[1]=d.y; dv[2]=d.z; dv[3]=d.w;
        }
      } else {
        cntv = 0;
        for (int t = 0; t < 4; ++t){
          int i = i0 + t;
          if (i >= MM) break;
          if (i < EE){
            if (i64){ sv[cntv] = ei[2 * i]; dv[cntv] = ei[2 * (EE + i)]; }
            else    { sv[cntv] = ei[i];     dv[cntv] = ei[EE + i]; }
          } else { sv[cntv] = i - EE; dv[cntv] = i - EE; }
          cntv++;
        }
      }
      for (int t = 0; t < cntv; ++t){
        int bin = dv[t] >> 8;
        int r = atomicAdd(&cnt[bin], 1);
        e1[offs[bin] + r] = ((unsigned)sv[t] << 8) | ((unsigned)dv[t] & 255u);
      }
    }
    return;
  }
  // ---- GEMM1 (MFMA, zero LDS) + fused att1 ----
  int bf = detect_bf((const u16*)xv);
  int tid = threadIdx.x;
  int wv = tid >> 6, l = tid & 63;
  int lm = l & 15, lk = l >> 4;          // lk 0..3
  int M0 = (b - NBLK) * 64 + wv * 16;
  int row = M0 + lm; if (row >= n) row = n - 1;
  bf16x8 a0, a1;
  if (bf){
    const u16* xp = (const u16*)xv + (size_t)row * 64;
    union { uint4 u; bf16x8 v; } c0, c1;
    c0.u = *(const uint4*)&xp[lk * 8];
    c1.u = *(const uint4*)&xp[32 + lk * 8];
    a0 = c0.v; a1 = c1.v;
  } else {
    const float* xp = (const float*)xv + (size_t)row * 64;
    float4 f0 = *(const float4*)&xp[lk * 8];
    float4 f1 = *(const float4*)&xp[lk * 8 + 4];
    float4 f2 = *(const float4*)&xp[32 + lk * 8];
    float4 f3 = *(const float4*)&xp[32 + lk * 8 + 4];
    union { u16 s[8]; bf16x8 v; } p0, p1;
    p0.s[0]=(u16)f2bf(f0.x); p0.s[1]=(u16)f2bf(f0.y); p0.s[2]=(u16)f2bf(f0.z); p0.s[3]=(u16)f2bf(f0.w);
    p0.s[4]=(u16)f2bf(f1.x); p0.s[5]=(u16)f2bf(f1.y); p0.s[6]=(u16)f2bf(f1.z); p0.s[7]=(u16)f2bf(f1.w);
    p1.s[0]=(u16)f2bf(f2.x); p1.s[1]=(u16)f2bf(f2.y); p1.s[2]=(u16)f2bf(f2.z); p1.s[3]=(u16)f2bf(f2.w);
    p1.s[4]=(u16)f2bf(f3.x); p1.s[5]=(u16)f2bf(f3.y); p1.s[6]=(u16)f2bf(f3.z); p1.s[7]=(u16)f2bf(f3.w);
    a0 = p0.v; a1 = p1.v;
  }
  f32x4 acc[8];
  #pragma unroll
  for (int nt = 0; nt < 8; ++nt) acc[nt] = (f32x4){0.f, 0.f, 0.f, 0.f};
  #pragma unroll
  for (int nt = 0; nt < 8; ++nt){
    int col = nt * 16 + lm;
    union { uint4 u; bf16x8 v; } b0, b1;
    b0.u = *(const uint4*)&wt1[(size_t)col * 64 + lk * 8];
    b1.u = *(const uint4*)&wt1[(size_t)col * 64 + 32 + lk * 8];
    acc[nt] = __builtin_amdgcn_mfma_f32_16x16x32_bf16(a0, b0.v, acc[nt], 0, 0, 0);
    acc[nt] = __builtin_amdgcn_mfma_f32_16x16x32_bf16(a1, b1.v, acc[nt], 0, 0, 0);
  }
  float ps0[4] = {0,0,0,0}, pd0[4] = {0,0,0,0}, ps1[4] = {0,0,0,0}, pd1[4] = {0,0,0,0};
  #pragma unroll
  for (int nt = 0; nt < 8; ++nt){
    int col = nt * 16 + lm;
    float aw = asw[col], dw = adw[col];
    #pragma unroll
    for (int i = 0; i < 4; ++i){
      float v = acc[nt][i];
      if (nt < 4){ ps0[i] += v * aw; pd0[i] += v * dw; }
      else       { ps1[i] += v * aw; pd1[i] += v * dw; }
    }
  }
  #pragma unroll
  for (int mk = 8; mk >= 1; mk >>= 1){
    #pragma unroll
    for (int i = 0; i < 4; ++i){
      ps0[i] += __shfl_xor(ps0[i], mk, 64); pd0[i] += __shfl_xor(pd0[i], mk, 64);
      ps1[i] += __shfl_xor(ps1[i], mk, 64); pd1[i] += __shfl_xor(pd1[i], mk, 64);
    }
  }
  #pragma unroll
  for (int nt = 0; nt < 8; ++nt){
    int col = nt * 16 + lm;
    #pragma unroll
    for (int i = 0; i < 4; ++i){
      int r = M0 + lk * 4 + i;
      if (r < n) h1bf[(size_t)r * 128 + col] = (u16)f2bf(acc[nt][i]);
    }
  }
  if (lm == 0){
    #pragma unroll
    for (int i = 0; i < 4; ++i){
      int r = M0 + lk * 4 + i;
      if (r < n){
        AS[r * 2] = ps0[i]; AS[r * 2 + 1] = ps1[i];
        AD[r * 2] = pd0[i]; AD[r * 2 + 1] = pd1[i];
      }
    }
  }
}

// ---------------- sort pass B: one block per 256-node bucket ----------------
__global__ __launch_bounds__(256) void k_pass2(const unsigned* __restrict__ e1, const int* __restrict__ incl,
                                               const int* __restrict__ ghist, const int* __restrict__ bsums,
                                               int* __restrict__ csr, int* __restrict__ rp){
  __shared__ int hh[256];
  __shared__ int cc[256];
  int bu = blockIdx.x;
  int t = threadIdx.x;
  int s = off1_at(incl, ghist, bsums, bu * NBLK);          // uniform -> scalar loads
  int e = off1_at(incl, ghist, bsums, (bu + 1) * NBLK);
  hh[t] = 0; cc[t] = 0;
  __syncthreads();
  for (int j = s + t; j < e; j += 256)
    atomicAdd(&hh[e1[j] & 255u], 1);
  __syncthreads();
  int own = hh[t];
  for (int off = 1; off < 256; off <<= 1){
    int x = (t >= off) ? hh[t - off] : 0;
    __syncthreads();
    hh[t] += x;
    __syncthreads();
  }
  int excl = hh[t] - own;
  hh[t] = excl;
  int node = (bu << 8) + t;
  if (node < NN) rp[node] = s + excl;
  if (bu == 0 && t == 0) rp[NN] = MM;
  __syncthreads();
  for (int j = s + t; j < e; j += 256){
    unsigned kv = e1[j];
    int d = kv & 255u;
    int r = atomicAdd(&cc[d], 1);
    csr[s + hh[d] + r] = (int)(kv >> 8);
  }
}

// ---------------- layer-1 aggregation: 2 nodes/wave, 4 gathers in flight -> h1bbf (bf16) ----------------
__global__ __launch_bounds__(256) void k_agg1(const u16* __restrict__ h1bf, const int* __restrict__ rp,
                                              const int* __restrict__ csr, const float* __restrict__ AS,
                                              const float* __restrict__ AD, const float* __restrict__ b1,
                                              u16* __restrict__ out, int n){
  int tid = threadIdx.x;
  int wid = (blockIdx.x * 256 + tid) >> 6;
  int h = (tid >> 5) & 1;
  int l5 = tid & 31;
  int node = wid * 2 + h;
  bool valid = node < n;
  if (!valid) node = n - 1;
  int g = l5 >> 4, u = l5 & 15;
  int hb = h * 32;
  int beg = rp[node], end = rp[node + 1];
  float2 adv = *(const float2*)&AD[node * 2];
  f32x2v acc[4] = {{0,0},{0,0},{0,0},{0,0}};
  float zp0 = 0.f, zp1 = 0.f;
  for (int c = beg; c < end; c += 32){
    int m = end - c; if (m > 32) m = 32;
    int s_l = 0; float w0_l = 0.f, w1_l = 0.f;
    if (l5 < m){
      s_l = csr[c + l5];
      float2 as2 = *(const float2*)&AS[s_l * 2];
      float e0 = as2.x + adv.x; e0 = fmaxf(e0, 0.2f * e0);
      float e1 = as2.y + adv.y; e1 = fmaxf(e1, 0.2f * e1);
      w0_l = __expf(e0); w1_l = __expf(e1);
    }
    zp0 += w0_l; zp1 += w1_l;
    for (int jj = 0; jj < m; jj += 8){
      int eA = jj + g, eB = jj + 2 + g, eC = jj + 4 + g, eD = jj + 6 + g;
      bool vA = eA < m, vB = eB < m, vC = eC < m, vD = eD < m;
      int sA = __shfl(s_l, hb + eA, 64), sB = __shfl(s_l, hb + eB, 64);
      int sC = __shfl(s_l, hb + eC, 64), sD = __shfl(s_l, hb + eD, 64);
      float wA0 = __shfl(w0_l, hb + eA, 64), wA1 = __shfl(w1_l, hb + eA, 64);
      float wB0 = __shfl(w0_l, hb + eB, 64), wB1 = __shfl(w1_l, hb + eB, 64);
      float wC0 = __shfl(w0_l, hb + eC, 64), wC1 = __shfl(w1_l, hb + eC, 64);
      float wD0 = __shfl(w0_l, hb + eD, 64), wD1 = __shfl(w1_l, hb + eD, 64);
      uint4 qA, qB, qC, qD;
      if (vA) qA = *(const uint4*)&h1bf[(size_t)sA * 128 + u * 8];
      if (vB) qB = *(const uint4*)&h1bf[(size_t)sB * 128 + u * 8];
      if (vC) qC = *(const uint4*)&h1bf[(size_t)sC * 128 + u * 8];
      if (vD) qD = *(const uint4*)&h1bf[(size_t)sD * 128 + u * 8];
      if (vA) acc_bf8p(acc, qA, (u < 8) ? wA0 : wA1);
      if (vB) acc_bf8p(acc, qB, (u < 8) ? wB0 : wB1);
      if (vC) acc_bf8p(acc, qC, (u < 8) ? wC0 : wC1);
      if (vD) acc_bf8p(acc, qD, (u < 8) ? wD0 : wD1);
    }
  }
  #pragma unroll
  for (int k = 0; k < 4; ++k){
    acc[k][0] += __shfl_xor(acc[k][0], 16, 64);
    acc[k][1] += __shfl_xor(acc[k][1], 16, 64);
  }
  float z0 = hwred(zp0), z1 = hwred(zp1);
  float rz = (u < 8) ? (1.f / (z0 + 1e-16f)) : (1.f / (z1 + 1e-16f));
  if (g == 0 && valid){
    float4 ba = *(const float4*)&b1[u * 8];
    float4 bb = *(const float4*)&b1[u * 8 + 4];
    float o0 = eluf(acc[0][0] * rz + ba.x), o1 = eluf(acc[0][1] * rz + ba.y);
    float o2 = eluf(acc[1][0] * rz + ba.z), o3 = eluf(acc[1][1] * rz + ba.w);
    float o4 = eluf(acc[2][0] * rz + bb.x), o5 = eluf(acc[2][1] * rz + bb.y);
    float o6 = eluf(acc[3][0] * rz + bb.z), o7 = eluf(acc[3][1] * rz + bb.w);
    uint4 pk;
    pk.x = f2bf(o0) | (f2bf(o1) << 16);
    pk.y = f2bf(o2) | (f2bf(o3) << 16);
    pk.z = f2bf(o4) | (f2bf(o5) << 16);
    pk.w = f2bf(o6) | (f2bf(o7) << 16);
    *(uint4*)&out[(size_t)node * 128 + u * 8] = pk;
  }
}

// ---------------- GEMM2 (MFMA) + fused att2: h2bf[N,64] = h1bbf@W2 ----------------
__global__ __launch_bounds__(256) void k_gemm2(const u16* __restrict__ hin, const u16* __restrict__ wt2,
                                               const float* __restrict__ asw, const float* __restrict__ adw,
                                               u16* __restrict__ h2bf, float* __restrict__ AS, float* __restrict__ AD,
                                               int n){
  int tid = threadIdx.x;
  int wv = tid >> 6, l = tid & 63;
  int lm = l & 15, lk = l >> 4;
  int M0 = blockIdx.x * 64 + wv * 16;
  int row = M0 + lm; if (row >= n) row = n - 1;
  const u16* hp = hin + (size_t)row * 128;
  bf16x8 a[4];
  #pragma unroll
  for (int kt = 0; kt < 4; ++kt){
    union { uint4 u; bf16x8 v; } c;
    c.u = *(const uint4*)&hp[kt * 32 + lk * 8];
    a[kt] = c.v;
  }
  f32x4 acc[4];
  #pragma unroll
  for (int nt = 0; nt < 4; ++nt) acc[nt] = (f32x4){0.f, 0.f, 0.f, 0.f};
  #pragma unroll
  for (int nt = 0; nt < 4; ++nt){
    int col = nt * 16 + lm;
    #pragma unroll
    for (int kt = 0; kt < 4; ++kt){
      union { uint4 u; bf16x8 v; } b;
      b.u = *(const uint4*)&wt2[(size_t)col * 128 + kt * 32 + lk * 8];
      acc[nt] = __builtin_amdgcn_mfma_f32_16x16x32_bf16(a[kt], b.v, acc[nt], 0, 0, 0);
    }
  }
  float ps[4] = {0,0,0,0}, pd[4] = {0,0,0,0};
  #pragma unroll
  for (int nt = 0; nt < 4; ++nt){
    int col = nt * 16 + lm;
    float aw = asw[col], dw = adw[col];
    #pragma unroll
    for (int i = 0; i < 4; ++i){
      float v = acc[nt][i];
      ps[i] += v * aw; pd[i] += v * dw;
    }
  }
  #pragma unroll
  for (int mk = 8; mk >= 1; mk >>= 1){
    #pragma unroll
    for (int i = 0; i < 4; ++i){
      ps[i] += __shfl_xor(ps[i], mk, 64); pd[i] += __shfl_xor(pd[i], mk, 64);
    }
  }
  #pragma unroll
  for (int nt = 0; nt < 4; ++nt){
    int col = nt * 16 + lm;
    #pragma unroll
    for (int i = 0; i < 4; ++i){
      int r = M0 + lk * 4 + i;
      if (r < n) h2bf[(size_t)r * 64 + col] = (u16)f2bf(acc[nt][i]);
    }
  }
  if (lm == 0){
    #pragma unroll
    for (int i = 0; i < 4; ++i){
      int r = M0 + lk * 4 + i;
      if (r < n){ AS[r] = ps[i]; AD[r] = pd[i]; }
    }
  }
}

// ---------------- layer-2 aggregation (pure gather, 4 in flight) -> hb bf16 ----------------
__global__ __launch_bounds__(256) void k_agg2(const u16* __restrict__ h2bf, const int* __restrict__ rp,
                                              const int* __restrict__ csr, const float* __restrict__ AS,
                                              const float* __restrict__ AD, const float* __restrict__ b2,
                                              u16* __restrict__ hb, int n){
  int node = (blockIdx.x * blockDim.x + threadIdx.x) >> 6;
  int lane = threadIdx.x & 63;
  if (node >= n) return;
  int g = lane >> 3, u = lane & 7;
  int beg = rp[node], end = rp[node + 1];
  float ad = AD[node];
  f32x2v acc[4] = {{0,0},{0,0},{0,0},{0,0}};
  float zp = 0.f;
  for (int c = beg; c < end; c += 64){
    int m = end - c; if (m > 64) m = 64;
    int s_l = 0; float w_l = 0.f;
    if (lane < m){
      s_l = csr[c + lane];
      float e = AS[s_l] + ad; e = fmaxf(e, 0.2f * e);
      w_l = __expf(e);
    }
    zp += w_l;
    for (int jj = 0; jj < m; jj += 32){
      int eA = jj + g, eB = jj + 8 + g, eC = jj + 16 + g, eD = jj + 24 + g;
      bool vA = eA < m, vB = eB < m, vC = eC < m, vD = eD < m;
      int sA = __shfl(s_l, eA, 64), sB = __shfl(s_l, eB, 64);
      int sC = __shfl(s_l, eC, 64), sD = __shfl(s_l, eD, 64);
      float wA = __shfl(w_l, eA, 64), wB = __shfl(w_l, eB, 64);
      float wC = __shfl(w_l, eC, 64), wD = __shfl(w_l, eD, 64);
      uint4 qA, qB, qC, qD;
      if (vA) qA = *(const uint4*)&h2bf[(size_t)sA * 64 + u * 8];
      if (vB) qB = *(const uint4*)&h2bf[(size_t)sB * 64 + u * 8];
      if (vC) qC = *(const uint4*)&h2bf[(size_t)sC * 64 + u * 8];
      if (vD) qD = *(const uint4*)&h2bf[(size_t)sD * 64 + u * 8];
      if (vA) acc_bf8p(acc, qA, wA);
      if (vB) acc_bf8p(acc, qB, wB);
      if (vC) acc_bf8p(acc, qC, wC);
      if (vD) acc_bf8p(acc, qD, wD);
    }
  }
  #pragma unroll
  for (int mk = 8; mk <= 32; mk <<= 1){
    #pragma unroll
    for (int k = 0; k < 4; ++k){
      acc[k][0] += __shfl_xor(acc[k][0], mk, 64);
      acc[k][1] += __shfl_xor(acc[k][1], mk, 64);
    }
  }
  float z = wred(zp);
  float rz = 1.f / (z + 1e-16f);
  if (g == 0){
    float4 ba = *(const float4*)&b2[u * 8];
    float4 bb = *(const float4*)&b2[u * 8 + 4];
    float o0 = eluf(acc[0][0] * rz + ba.x), o1 = eluf(acc[0][1] * rz + ba.y);
    float o2 = eluf(acc[1][0] * rz + ba.z), o3 = eluf(acc[1][1] * rz + ba.w);
    float o4 = eluf(acc[2][0] * rz + bb.x), o5 = eluf(acc[2][1] * rz + bb.y);
    float o6 = eluf(acc[3][0] * rz + bb.z), o7 = eluf(acc[3][1] * rz + bb.w);
    uint4 pk;
    pk.x = f2bf(o0) | (f2bf(o1) << 16);
    pk.y = f2bf(o2) | (f2bf(o3) << 16);
    pk.z = f2bf(o4) | (f2bf(o5) << 16);
    pk.w = f2bf(o6) | (f2bf(o7) << 16);
    *(uint4*)&hb[(size_t)node * 64 + u * 8] = pk;
  }
}

// ---------------- MLP head: node-per-lane, scalar-load weights, zero LDS ----------------
__global__ __launch_bounds__(256) void k_mlp(const u16* __restrict__ hb, const u16* __restrict__ x16,
                                             const float* __restrict__ m1w, const float* __restrict__ m1b,
                                             const float* __restrict__ m2w, const float* __restrict__ m2b,
                                             void* __restrict__ outv, int n){
  int bf = detect_bf(x16);
  int node = blockIdx.x * 256 + threadIdx.x;
  bool act = node < n;
  const u16* hp = hb + (size_t)(act ? node : 0) * 64;
  float acc[64];
  #pragma unroll
  for (int j = 0; j < 64; ++j) acc[j] = m1b[j];
  #pragma unroll
  for (int kc = 0; kc < 8; ++kc){
    uint4 q = *(const uint4*)&hp[kc * 8];
    float hk[8] = {bf2f_lo(q.x), bf2f_hi(q.x), bf2f_lo(q.y), bf2f_hi(q.y),
                   bf2f_lo(q.z), bf2f_hi(q.z), bf2f_lo(q.w), bf2f_hi(q.w)};
    #pragma unroll
    for (int t = 0; t < 8; ++t){
      const float* wr = &m1w[(kc * 8 + t) * 64];
      #pragma unroll
      for (int j = 0; j < 64; ++j) acc[j] += hk[t] * wr[j];
    }
  }
  float o[8];
  #pragma unroll
  for (int c = 0; c < 8; ++c) o[c] = m2b[c];
  #pragma unroll
  for (int j = 0; j < 64; ++j){
    float r = fmaxf(acc[j], 0.f);
    const float* w2r = &m2w[j * 8];
    #pragma unroll
    for (int c = 0; c < 8; ++c) o[c] += r * w2r[c];
  }
  if (act){
    if (bf){
      uint4 pk;
      pk.x = f2bf(fmaxf(o[0], 0.f)) | (f2bf(fmaxf(o[1], 0.f)) << 16);
      pk.y = f2bf(fmaxf(o[2], 0.f)) | (f2bf(fmaxf(o[3], 0.f)) << 16);
      pk.z = f2bf(fmaxf(o[4], 0.f)) | (f2bf(fmaxf(o[5], 0.f)) << 16);
      pk.w = f2bf(fmaxf(o[6], 0.f)) | (f2bf(fmaxf(o[7], 0.f)) << 16);
      *(uint4*)&((u16*)outv)[(size_t)node * 8] = pk;
    } else {
      float4 a, b;
      a.x = fmaxf(o[0], 0.f); a.y = fmaxf(o[1], 0.f); a.z = fmaxf(o[2], 0.f); a.w = fmaxf(o[3], 0.f);
      b.x = fmaxf(o[4], 0.f); b.y = fmaxf(o[5], 0.f); b.z = fmaxf(o[6], 0.f); b.w = fmaxf(o[7], 0.f);
      *(float4*)&((float*)outv)[(size_t)node * 8]     = a;
      *(float4*)&((float*)outv)[(size_t)node * 8 + 4] = b;
    }
  }
}

// ---------------- host ----------------
extern "C" void kernel_launch(void* const* d_in, const int* in_sizes, int n_in,
                              void* d_out, int out_size, void* d_ws, size_t ws_size,
                              hipStream_t stream){
  const void* x   = d_in[0];
  const void* ei  = d_in[1];

  char* base = (char*)d_ws;
  size_t off = 0;
  auto alloc = [&](size_t bytes) -> void* {
    void* p = base + off;
    off += (bytes + 255) & ~(size_t)255;
    return p;
  };
  float* wbuf  = (float*)alloc(21640 * 4);
  u16*   wt1   = (u16*)alloc(8192 * 2);
  u16*   wt2   = (u16*)alloc(8192 * 2);
  u16*   h1bf  = (u16*)alloc((size_t)NN * 128 * 2);   // h2bf aliases later
  u16*   h1bbf = (u16*)alloc((size_t)NN * 128 * 2);
  u16*   hbuf  = (u16*)alloc((size_t)NN * 64 * 2);
  float* AS1   = (float*)alloc((size_t)NN * 2 * 4);
  float* AD1   = (float*)alloc((size_t)NN * 2 * 4);
  float* AS2   = (float*)alloc((size_t)NN * 4);
  float* AD2   = (float*)alloc((size_t)NN * 4);
  unsigned* e1 = (unsigned*)alloc((size_t)MM * 4);
  int*   csr   = (int*)alloc((size_t)MM * 4);
  int*   rp    = (int*)alloc((size_t)(NN + 1) * 4);
  int*   ghist = (int*)alloc((size_t)N1 * 4);
  int*   incl  = (int*)alloc((size_t)N1 * 4);
  int*   bsums = (int*)alloc(128 * 4);

  if (off > ws_size){
    int nf = out_size / 2;
    k_fill<<<(nf + 255) / 256, 256, 0, stream>>>((float*)d_out, nf);
    return;
  }

  float* AS1W = wbuf + 8192;
  float* AD1W = wbuf + 8320;
  float* B1f  = wbuf + 8448;
  float* AS2W = wbuf + 16768;
  float* AD2W = wbuf + 16832;
  float* B2f  = wbuf + 16896;
  float* M1W  = wbuf + 16960;
  float* M1B  = wbuf + 21056;
  float* M2W  = wbuf + 21120;
  float* M2B  = wbuf + 21632;
  u16*   h2bf = h1bf;   // alias: h1bf dead once agg1 completes

  const int NBCONV = (NCONV + 255) / 256;   // 149

  k_hist1<<<NBLK + NBCONV, 256, 0, stream>>>((const int*)ei, (const u16*)x, ghist,
                                             d_in[2], d_in[3], d_in[4], d_in[5], d_in[6],
                                             d_in[7], d_in[8], d_in[9], d_in[10], d_in[11],
                                             d_in[12], d_in[13], wbuf, wt1, wt2);
  k_gscan1<<<N1 / 1024, 1024, 0, stream>>>(ghist, incl, bsums);
  k_scan2<<<1, 128, 0, stream>>>(bsums, N1 / 1024);
  k_scat_gemm1<<<NBLK + NBG1, 256, 0, stream>>>((const int*)ei, incl, ghist, bsums, e1,
                                                x, wt1, AS1W, AD1W, h1bf, AS1, AD1, NN);
  k_pass2<<<NBKT, 256, 0, stream>>>(e1, incl, ghist, bsums, csr, rp);

  k_agg1<<<(NN / 2 + 3) / 4, 256, 0, stream>>>(h1bf, rp, csr, AS1, AD1, B1f, h1bbf, NN);

  k_gemm2<<<(NN + 63) / 64, 256, 0, stream>>>(h1bbf, wt2, AS2W, AD2W, h2bf, AS2, AD2, NN);
  k_agg2<<<(NN + 3) / 4, 256, 0, stream>>>(h2bf, rp, csr, AS2, AD2, B2f, hbuf, NN);
  k_mlp<<<(NN + 255) / 256, 256, 0, stream>>>(hbuf, (const u16*)x, M1W, M1B, M2W, M2B, d_out, NN);
}